// Round 8
// baseline (69.306 us; speedup 1.0000x reference)
//
#include <hip/hip_runtime.h>

// features [B=32, C=2048, T=8, H=7, W=7] f32, W [C=2048, K=400] f32,
// labels [B] int, unchanged_mask [B] int.
// z_grads[b,c,:,:,:] = W[c, labels[b]] / 392  (grad of avgpool+linear pick).
// quantile(0.77, N=802816, linear): idx 618167.55 -> both floor/ceil fall in
// the 392-block of sorted channel rank 1576 -> thr[b] = kth(W[:,l_b]/392, 1576).
#define B_  32
#define C_  2048
#define K_  400
#define POOL_N 392.0f
#define RANK_ 1576

// ---- Kernel A: per-batch threshold via distributed rank-count -------------
__global__ __launch_bounds__(256) void thr_kernel(
    const float* __restrict__ Wm, const int* __restrict__ labels,
    float* __restrict__ thr_out) {
  const int b   = blockIdx.x >> 3;
  const int s   = blockIdx.x & 7;
  const int tid = threadIdx.x;
  __shared__ __align__(16) float z[C_];

  const int l = labels[b];
  for (int i = tid; i < C_; i += 256) z[i] = Wm[i * K_ + l] / POOL_N;
  __syncthreads();

  const float zi = z[s * 256 + tid];
  int cl = 0, ce = 0;
  #pragma unroll 4
  for (int j = 0; j < C_; j += 4) {
    const float4 v = *reinterpret_cast<const float4*>(&z[j]);  // broadcast
    cl += (v.x <  zi) + (v.y <  zi) + (v.z <  zi) + (v.w <  zi);
    ce += (v.x == zi) + (v.y == zi) + (v.z == zi) + (v.w == zi);
  }
  // Exactly one distinct value satisfies; tied threads write identical bits.
  if (cl <= RANK_ && RANK_ < cl + ce) thr_out[b] = zi;
}

// ---- Kernel B: materialize per-(b,c) factor table (256 KB, L2-hot) --------
__global__ __launch_bounds__(256) void factor_kernel(
    const float* __restrict__ Wm, const int* __restrict__ labels,
    const int* __restrict__ unch, const float* __restrict__ thr,
    float* __restrict__ factor) {
  const int b   = blockIdx.x;
  const int tid = threadIdx.x;
  const int l = labels[b];
  const bool unchanged = (unch[b] != 0);
  const float t = thr[b];
  const float scale = (float)(1.0 / 0.77);
  for (int c = tid; c < C_; c += 256) {
    const float zz = Wm[c * K_ + l] / POOL_N;
    // strict '>': the rank-1576 element itself is KEPT.
    factor[b * C_ + c] = unchanged ? 1.0f : ((zz > t) ? 0.0f : scale);
  }
}

// ---- Kernel C: streaming apply, single broadcast factor load --------------
__global__ __launch_bounds__(256) void apply_kernel(
    const float* __restrict__ in, const float* __restrict__ factor,
    float* __restrict__ out, int nvec) {
  const int stride = gridDim.x * 256;
  for (int v = blockIdx.x * 256 + threadIdx.x; v < nvec; v += stride) {
    // 392 floats per (b,c) = 98 float4s: each vec4 lies within one (b,c).
    const float s = factor[v / 98];   // magic-mul; 1-2 distinct addrs per wave
    float4 x = reinterpret_cast<const float4*>(in)[v];
    x.x *= s; x.y *= s; x.z *= s; x.w *= s;
    reinterpret_cast<float4*>(out)[v] = x;
  }
}

extern "C" void kernel_launch(void* const* d_in, const int* in_sizes, int n_in,
                              void* d_out, int out_size, void* d_ws, size_t ws_size,
                              hipStream_t stream) {
  const float* features = (const float*)d_in[0];
  const float* Wm       = (const float*)d_in[1];
  const int*   labels   = (const int*)d_in[2];
  const int*   unch     = (const int*)d_in[3];
  float* out = (float*)d_out;
  float* thr    = (float*)d_ws;            // 32 floats
  float* factor = (float*)d_ws + 64;       // B_*C_ floats = 256 KiB

  thr_kernel<<<B_ * 8, 256, 0, stream>>>(Wm, labels, thr);
  factor_kernel<<<B_, 256, 0, stream>>>(Wm, labels, unch, thr, factor);

  const int nvec = in_sizes[0] / 4;  // 6,422,528 float4s = 3136*256*8 exactly
  apply_kernel<<<3136, 256, 0, stream>>>(features, factor, out, nvec);
}